// Round 1
// baseline (880.359 us; speedup 1.0000x reference)
//
#include <hip/hip_runtime.h>

// Problem constants (match reference: B=32, T=4096, D=1024)
constexpr int Bc    = 32;
constexpr int Tc    = 4096;
constexpr int Dc    = 1024;
constexpr int D4    = Dc / 4;     // float4 columns per row = 256
constexpr int CHUNK = 128;        // t-rows per block

// d_out is poisoned 0xAA before every timed launch: zero it first.
__global__ __launch_bounds__(256) void zero_out_kernel(float* __restrict__ out) {
    int i = blockIdx.x * 256 + threadIdx.x;
    if (i < Bc * Dc) out[i] = 0.0f;
}

// Softmax over the singleton axis == 1.0 everywhere, so the reference output
// is exactly out[b,d] = sum_t values[b,t,d]. Pure streaming reduction.
// Block = 256 threads; thread i owns float4 column i of the 1024-wide row.
// Grid = B * (T/CHUNK) blocks; each block reduces CHUNK contiguous rows,
// then does one HW fp32 atomic add per owned element (32-way contention).
__global__ __launch_bounds__(256) void sum_values_kernel(
        const float* __restrict__ values, float* __restrict__ out) {
    constexpr int chunks_per_b = Tc / CHUNK;            // 32
    const int b     = blockIdx.x / chunks_per_b;
    const int chunk = blockIdx.x % chunks_per_b;
    const int t0    = chunk * CHUNK;
    const int d4    = threadIdx.x;                      // 0..255

    const float4* base = reinterpret_cast<const float4*>(values)
                       + (size_t)b * Tc * D4
                       + (size_t)t0 * D4
                       + d4;

    // 4 independent accumulators -> 4 outstanding float4 loads per iter (ILP)
    float4 a0 = make_float4(0.f, 0.f, 0.f, 0.f);
    float4 a1 = a0, a2 = a0, a3 = a0;

    #pragma unroll 4
    for (int t = 0; t < CHUNK; t += 4) {
        float4 v0 = base[(size_t)(t + 0) * D4];
        float4 v1 = base[(size_t)(t + 1) * D4];
        float4 v2 = base[(size_t)(t + 2) * D4];
        float4 v3 = base[(size_t)(t + 3) * D4];
        a0.x += v0.x; a0.y += v0.y; a0.z += v0.z; a0.w += v0.w;
        a1.x += v1.x; a1.y += v1.y; a1.z += v1.z; a1.w += v1.w;
        a2.x += v2.x; a2.y += v2.y; a2.z += v2.z; a2.w += v2.w;
        a3.x += v3.x; a3.y += v3.y; a3.z += v3.z; a3.w += v3.w;
    }

    const float sx = (a0.x + a1.x) + (a2.x + a3.x);
    const float sy = (a0.y + a1.y) + (a2.y + a3.y);
    const float sz = (a0.z + a1.z) + (a2.z + a3.z);
    const float sw = (a0.w + a1.w) + (a2.w + a3.w);

    float* o = out + (size_t)b * Dc + (size_t)d4 * 4;
    // HW global_atomic_add_f32 (values are normal floats; no denormal concern)
    unsafeAtomicAdd(o + 0, sx);
    unsafeAtomicAdd(o + 1, sy);
    unsafeAtomicAdd(o + 2, sz);
    unsafeAtomicAdd(o + 3, sw);
}

extern "C" void kernel_launch(void* const* d_in, const int* in_sizes, int n_in,
                              void* d_out, int out_size, void* d_ws, size_t ws_size,
                              hipStream_t stream) {
    // Input order per setup_inputs(): query [B,D], keys [B,T,D], values [B,T,D], W [T,1]
    // query/keys/W are numerically dead (softmax over singleton axis == 1).
    const float* values = (const float*)d_in[2];
    float* out = (float*)d_out;

    zero_out_kernel<<<(Bc * Dc + 255) / 256, 256, 0, stream>>>(out);
    sum_values_kernel<<<Bc * (Tc / CHUNK), 256, 0, stream>>>(values, out);
}